// Round 1
// baseline (354.615 us; speedup 1.0000x reference)
//
#include <hip/hip_runtime.h>
#include <cfloat>
#include <cmath>

#define NT 256
#define TOPK 2
#define VDIM 4096            // fixed by the problem: y_pred is [B, 4096]
#define F4_PER_THREAD (VDIM / 4 / NT)   // 4

// One block per row: register-resident two-pass softmax + gather.
__global__ __launch_bounds__(NT) void row_loss_kernel(
    const float* __restrict__ y, const int* __restrict__ tgt,
    const float* __restrict__ w, float* __restrict__ row_out)
{
    const int b   = blockIdx.x;
    const int tid = threadIdx.x;
    const int wave = tid >> 6;
    const int lane = tid & 63;
    const float* row = y + (size_t)b * VDIM;

    // Up-front scalar loads (latency hidden behind the streaming loads below).
    const int t0 = tgt[TOPK * b + 0];
    const int t1 = tgt[TOPK * b + 1];
    const float w0 = w[0], w1 = w[1];
    const float y0 = row[t0 < 0 ? 0 : t0];
    const float y1 = row[t1 < 0 ? 0 : t1];

    // Stream the row into registers: 4 coalesced float4 per thread = 16 floats.
    float4 r[F4_PER_THREAD];
    const float4* row4 = (const float4*)row;
#pragma unroll
    for (int t = 0; t < F4_PER_THREAD; ++t)
        r[t] = row4[tid + t * NT];

    // ---- pass 1: max ----
    float m = -FLT_MAX;
#pragma unroll
    for (int t = 0; t < F4_PER_THREAD; ++t)
        m = fmaxf(m, fmaxf(fmaxf(r[t].x, r[t].y), fmaxf(r[t].z, r[t].w)));
#pragma unroll
    for (int off = 32; off; off >>= 1)
        m = fmaxf(m, __shfl_xor(m, off, 64));

    __shared__ float s_partial[NT / 64];
    __shared__ float s_bcast;
    if (lane == 0) s_partial[wave] = m;
    __syncthreads();
    if (tid == 0)
        s_bcast = fmaxf(fmaxf(s_partial[0], s_partial[1]),
                        fmaxf(s_partial[2], s_partial[3]));
    __syncthreads();
    m = s_bcast;
    __syncthreads();   // protect s_partial reuse below

    // ---- pass 2: sum(exp) from registers ----
    float s = 0.f;
#pragma unroll
    for (int t = 0; t < F4_PER_THREAD; ++t)
        s += __expf(r[t].x - m) + __expf(r[t].y - m) +
             __expf(r[t].z - m) + __expf(r[t].w - m);
#pragma unroll
    for (int off = 32; off; off >>= 1)
        s += __shfl_xor(s, off, 64);
    if (lane == 0) s_partial[wave] = s;
    __syncthreads();

    if (tid == 0) {
        const float Z = s_partial[0] + s_partial[1] + s_partial[2] + s_partial[3];
        float dot = 0.f;
        int   len = 0;
        if (t0 != -1) { dot += w0 * __expf(y0 - m); ++len; }
        if (t1 != -1) { dot += w1 * __expf(y1 - m); ++len; }
        dot /= Z;
        // discount: len==2 -> 1 ; len==1 -> 1-w1 ; len==0 -> 1 (suffix[TOPK]=0)
        float discount = (len == 1) ? (1.0f - w1) : 1.0f;
        float per = -fmaxf(logf(dot / discount), -100.0f);
        row_out[b] = per;
    }
}

// Single-block reduction of B per-row losses -> out[0] = sum/B.
__global__ __launch_bounds__(NT) void reduce_kernel(
    const float* __restrict__ rows, float* __restrict__ out, int B)
{
    const int tid = threadIdx.x;
    float s = 0.f;
    const float4* rows4 = (const float4*)rows;
    const int n4 = B / 4;
    for (int i = tid; i < n4; i += NT) {
        float4 v = rows4[i];
        s += v.x + v.y + v.z + v.w;
    }
#pragma unroll
    for (int off = 32; off; off >>= 1)
        s += __shfl_xor(s, off, 64);
    __shared__ float s_partial[NT / 64];
    if ((tid & 63) == 0) s_partial[tid >> 6] = s;
    __syncthreads();
    if (tid == 0)
        out[0] = (s_partial[0] + s_partial[1] + s_partial[2] + s_partial[3])
                 / (float)B;
}

extern "C" void kernel_launch(void* const* d_in, const int* in_sizes, int n_in,
                              void* d_out, int out_size, void* d_ws, size_t ws_size,
                              hipStream_t stream) {
    const float* y_pred = (const float*)d_in[0];
    const int*   target = (const int*)d_in[1];
    const float* weight = (const float*)d_in[2];
    float* out  = (float*)d_out;
    float* rows = (float*)d_ws;           // B floats of scratch

    const int B = in_sizes[1] / TOPK;     // 16384

    row_loss_kernel<<<B, NT, 0, stream>>>(y_pred, target, weight, rows);
    reduce_kernel<<<1, NT, 0, stream>>>(rows, out, B);
}